// Round 17
// baseline (346.559 us; speedup 1.0000x reference)
//
#include <hip/hip_runtime.h>
#include <stdint.h>

// RPN RoI proposal -- R17: single DATAFLOW kernel (per-batch last-block
// chaining, rocPRIM-style) + 256B counter memset. No grid barriers: each
// block does P1(b,s); the 16th finisher of batch b (agent-scope acq_rel
// atomic + threadfence) continues through P2 sort -> P3 decode+supmat
// (ALL IN LDS, 17-word padded rows) -> P4 sweep -> output, overlapping
// other batches' P1. R16 proved phase logic correct at 256 threads but
// grid.sync serialized phases (101us); R14 pipeline = 75.7us with ~30us
// in node boundaries. This removes 3 boundaries AND the supmat global
// round-trip.
//  P1 (B*16 blocks x 256): threshold gather (bin>=CONS) -> bin-grouped
//     per-slice segments + per-slice 64-bin hist. key = flip(f32)<<32 |
//     bin<<20 | (0xFFFFF-idx): u64 desc == lax.top_k order w/ tie-break.
//  P2 (last block of b): scanned hist tables -> arithmetic scatter; per-
//     wave segment sorts -> LDS dest + g_sorted (fallback insurance).
//     Exact hist-2048 fallback in-branch (never taken).
//  P3 (same block): decode 512 ranks -> LDS box; suppression matrix
//     [512][17] in LDS (padded: conflict-free); diag col-words supT64.
//  P4 (same block, wave 0): chunked greedy sweep (ffs+ballot resolve,
//     LDS propagation); early-exit at 300; exact fallback via global
//     scratch (never taken); write clipped [300,4] zero-padded from LDS.

#define PRE 2000
#define POST 300
#define TILE 512
#define IOU_THR 0.7f
#define EPSV 1e-8f
#define SORTN 2048
#define NBINS 2048
#define DESTCAP 4096
#define CANDCAP 512
#define CONS 1984
#define SL 16
#define KBUF 768

typedef unsigned long long u64;

__device__ __forceinline__ uint32_t flip_f32(uint32_t b) {
    return b ^ ((uint32_t)((int32_t)b >> 31) | 0x80000000u);
}

__device__ __forceinline__ int bin_of(float s) {
    int bn = (int)(s * 2048.0f);
    return min(max(bn, 0), NBINS - 1);
}

__device__ __forceinline__ u64 make_key(float s, int idx, int bn) {
    uint32_t ub = flip_f32(__float_as_uint(s));
    return ((u64)ub << 32) | ((uint32_t)bn << 20) |
           (uint32_t)(0xFFFFF - idx);
}

__device__ __forceinline__ bool iou_gt(const float4& bi, float ai,
                                       const float4& bj, float aj) {
    float yy1 = fmaxf(bi.x, bj.x);
    float xx1 = fmaxf(bi.y, bj.y);
    float yy2 = fminf(bi.z, bj.z);
    float xx2 = fminf(bi.w, bj.w);
    float inter = fmaxf(yy2 - yy1, 0.f) * fmaxf(xx2 - xx1, 0.f);
    float iou = inter / (ai + aj - inter + EPSV);
    return iou > IOU_THR;
}

__device__ __forceinline__ float area_of(const float4& bx) {
    return fmaxf(bx.z - bx.x, 0.f) * fmaxf(bx.w - bx.y, 0.f);
}

__device__ __forceinline__ float4 decode_key(u64 key, const float4* dl,
                                             const float4* anchors, int N) {
    uint32_t idx = 0xFFFFFu - (uint32_t)(key & 0xFFFFFull);
    if (idx >= (uint32_t)N) return make_float4(0.f, 0.f, 0.f, 0.f);
    float4 d  = dl[idx];
    float4 an = anchors[idx];
    float ah  = an.z - an.x;
    float aw  = an.w - an.y;
    float acy = an.x + 0.5f * ah;
    float acx = an.y + 0.5f * aw;
    float h   = expf(d.z) * ah;
    float w   = expf(d.w) * aw;
    float cy  = d.x * ah + acy;
    float cx  = d.y * aw + acx;
    float y1  = cy - 0.5f * h;
    float x1  = cx - 0.5f * w;
    return make_float4(y1, x1, y1 + h, x1 + w);
}

__device__ __forceinline__ u64 cs_keep(u64 v, u64 pv, int i, int j, int k) {
    bool lower   = ((i & j) == 0);
    bool desc    = ((i & k) == 0);
    bool keepmax = (desc == lower);
    u64 mx = v > pv ? v : pv;
    u64 mn = v > pv ? pv : v;
    return keepmax ? mx : mn;
}

struct P1L {
    u64 keybuf[KBUF];
    u64 binbuf[KBUF];
    uint32_t hist64[64];
    int base64[64];
    uint32_t cur64[64];
    int kcnt;
};
struct P2L {
    u64 dest[DESTCAP];            // keys; fallback aliases sub-ranges
    int off[SL][64];
    int tot64[64];
    int segbase64[64];
    int flag, total, bsel, tprime, cnt, nc;
    uint32_t pivot;
};
struct PBL {                      // P3+P4 (same block)
    float4 box[TILE];             // 8 KB
    uint32_t supmat[TILE][17];    // 34.8 KB, padded: conflict-free
    u64 supT64[TILE];             // 4 KB diag col-words
    uint32_t kept[POST];
    u64 keepbits[TILE / 64];
    uint32_t fmask[(PRE - TILE + 31) / 32];
};
union FlowLDS { P1L p1; P2L p2; PBL pb; };   // ~48.4 KB

__global__ __launch_bounds__(256) void dataflow_kernel(
    const float4* __restrict__ score4,
    const float4* __restrict__ deltas,
    const float4* __restrict__ anchors,
    u64*      __restrict__ g_pairs,      // [B*SL*KBUF]
    int*      __restrict__ g_scnt,       // [B*SL]
    uint32_t* __restrict__ g_shist,      // [B*SL*64]
    u64*      __restrict__ g_sorted,     // [B*SORTN]
    int*      __restrict__ g_cnt,        // [B], pre-zeroed (memset node)
    float4*   __restrict__ out,          // [B*POST]
    int N)
{
    const int blk  = blockIdx.x;
    const int b    = blk / SL;
    const int s    = blk % SL;
    const int tid  = threadIdx.x;
    const int lane = tid & 63;
    const int wv4  = tid >> 6;           // wave 0..3
    const int F4PB = N >> 2;

    __shared__ FlowLDS u;
    __shared__ int sh_last;

    // ==================== P1: gather + per-slice binning ===================
    {
        const int F4PS = (F4PB + SL - 1) / SL;

        if (tid < 64) { u.p1.hist64[tid] = 0u; u.p1.cur64[tid] = 0u; }
        if (tid == 0) u.p1.kcnt = 0;
        __syncthreads();

        const float4* src = score4 + (size_t)b * F4PB;
        const int n0 = s * F4PS, n1 = min(n0 + F4PS, F4PB);
        for (int n = n0 + tid; n < n1; n += 256) {
            float4 v = src[n];
            float sv[4] = {v.x, v.y, v.z, v.w};
#pragma unroll
            for (int c = 0; c < 4; ++c) {
                int bn = bin_of(sv[c]);
                if (bn >= CONS) {
                    int q = atomicAdd(&u.p1.kcnt, 1);
                    if (q < KBUF) u.p1.keybuf[q] = make_key(sv[c], 4 * n + c, bn);
                }
            }
        }
        __syncthreads();

        const int raw = u.p1.kcnt;
        const int lc  = min(raw, KBUF);

        for (int i = tid; i < lc; i += 256) {
            int b64 = (int)((u.p1.keybuf[i] >> 20) & 0xFFFu) - CONS;
            atomicAdd(&u.p1.hist64[b64], 1u);
        }
        __syncthreads();

        if (tid < 64) {
            int h = (int)u.p1.hist64[lane];
            int ssum = h;
#pragma unroll
            for (int off = 1; off < 64; off <<= 1) {
                int t = __shfl_down(ssum, off, 64);
                if (lane + off < 64) ssum += t;
            }
            u.p1.base64[lane] = ssum - h;    // keys in bins > lane (desc)
        }
        __syncthreads();

        for (int i = tid; i < lc; i += 256) {
            u64 key = u.p1.keybuf[i];
            int b64 = (int)((key >> 20) & 0xFFFu) - CONS;
            int p = (int)atomicAdd(&u.p1.cur64[b64], 1u);
            u.p1.binbuf[u.p1.base64[b64] + p] = key;
        }
        __syncthreads();

        if (tid == 0) g_scnt[b * SL + s] = raw;
        if (tid < 64) g_shist[((size_t)b * SL + s) * 64 + tid] = u.p1.hist64[tid];
        u64* gp = g_pairs + ((size_t)b * SL + s) * KBUF;
        for (int i = tid; i < lc; i += 256) gp[i] = u.p1.binbuf[i];
    }

    // ---- last-block-of-batch detection (release -> acquire, agent scope) --
    __threadfence();
    if (tid == 0) {
        int old = __hip_atomic_fetch_add(&g_cnt[b], 1, __ATOMIC_ACQ_REL,
                                         __HIP_MEMORY_SCOPE_AGENT);
        sh_last = (old == SL - 1);
    }
    __syncthreads();
    if (!sh_last) return;               // non-last blocks exit (no waiting)
    __threadfence();                    // acquire all slices' writes

    // ==================== P2: scatter + segmented sort =====================
    {
        uint32_t* sh = (uint32_t*)u.p2.dest;   // shist staging alias (4 KB)
        for (int i = tid; i < SL * 64; i += 256)
            sh[i] = g_shist[(size_t)b * SL * 64 + i];
        if (tid == 0) {
            int f = 0;
            for (int s2 = 0; s2 < SL; ++s2)
                if (g_scnt[b * SL + s2] > KBUF) f = 1;
            u.p2.flag = f;
        }
        __syncthreads();

        if (tid < 64) {                  // wave 0: totals + suffix scan
            int acc = 0;
#pragma unroll
            for (int s2 = 0; s2 < SL; ++s2) acc += (int)sh[s2 * 64 + tid];
            u.p2.tot64[tid] = acc;
            if (acc > 128) u.p2.flag = 1;
            int ssum = acc;
#pragma unroll
            for (int off = 1; off < 64; off <<= 1) {
                int t = __shfl_down(ssum, off, 64);
                if (lane + off < 64) ssum += t;
            }
            u.p2.segbase64[tid] = ssum - acc;
            if (tid == 0) u.p2.total = ssum;
        }
        __syncthreads();
        const int total = u.p2.total;
        if (tid == 0 && (total < PRE || total > DESTCAP)) u.p2.flag = 1;
        for (int e = tid; e < SL * 64; e += 256) {
            int s2 = e >> 6, b64 = e & 63;
            int pre = 0;
            for (int s3 = 0; s3 < s2; ++s3) pre += (int)sh[s3 * 64 + b64];
            int srcb = 0;
            for (int b2 = b64 + 1; b2 < 64; ++b2) srcb += (int)sh[s2 * 64 + b2];
            u.p2.off[s2][b64] = u.p2.segbase64[b64] + pre - srcb;
        }
        __syncthreads();
        const bool flag = (u.p2.flag != 0);

        if (!flag) {
            // one-pass scatter; wave wv4 handles slices 4*wv4 .. 4*wv4+3
#pragma unroll
            for (int si = 0; si < 4; ++si) {
                int s2 = wv4 * 4 + si;
                const int cs = min(g_scnt[b * SL + s2], KBUF);
                const u64* gp = g_pairs + ((size_t)b * SL + s2) * KBUF;
                for (int i = lane; i < cs; i += 64) {
                    u64 key = gp[i];
                    int b64 = (int)((key >> 20) & 0xFFFu) - CONS;
                    u.p2.dest[u.p2.off[s2][b64] + i] = key;
                }
            }
            for (int q = total + tid; q < SORTN; q += 256) u.p2.dest[q] = 0ull;
            __syncthreads();
            for (int sgi = wv4; sgi < 64; sgi += 4) {
                int n = u.p2.tot64[sgi];
                if (n <= 0) continue;
                int base = u.p2.segbase64[sgi];
                if (n <= 64) {
                    u64 e = (lane < n) ? u.p2.dest[base + lane] : 0ull;
#pragma unroll
                    for (int k = 2; k <= 64; k <<= 1)
                        for (int j = k >> 1; j > 0; j >>= 1)
                            e = cs_keep(e, __shfl_xor(e, j, 64), lane, j, k);
                    if (lane < n) u.p2.dest[base + lane] = e;
                } else {                 // 65..128
                    u64 e0 = (lane < n) ? u.p2.dest[base + lane] : 0ull;
                    u64 e1 = (lane + 64 < n) ? u.p2.dest[base + lane + 64] : 0ull;
#pragma unroll
                    for (int k = 2; k <= 128; k <<= 1) {
                        for (int j = k >> 1; j > 0; j >>= 1) {
                            if (j == 64) {
                                u64 a = e0, c = e1;
                                e0 = cs_keep(a, c, lane, 64, k);
                                e1 = cs_keep(c, a, lane + 64, 64, k);
                            } else {
                                e0 = cs_keep(e0, __shfl_xor(e0, j, 64), lane, j, k);
                                e1 = cs_keep(e1, __shfl_xor(e1, j, 64), lane + 64, j, k);
                            }
                        }
                    }
                    if (lane < n) u.p2.dest[base + lane] = e0;
                    if (lane + 64 < n) u.p2.dest[base + lane + 64] = e1;
                }
            }
            __syncthreads();
            for (int r = tid; r < SORTN; r += 256)
                g_sorted[(size_t)b * SORTN + r] = u.p2.dest[r];
        } else {
            // ---- exact fallback (never taken): hist-2048 top-2000 ----
            uint32_t* hist2048 = (uint32_t*)&u.p2.dest[2048];
            u64*      cand     = &u.p2.dest[3072];
            for (int i = tid; i < NBINS; i += 256) hist2048[i] = 0u;
            if (tid == 0) { u.p2.cnt = 0; u.p2.nc = 0; }
            __syncthreads();
            const float4* src = score4 + (size_t)b * F4PB;
            for (int n = tid; n < F4PB; n += 256) {
                float4 v = src[n];
                atomicAdd(&hist2048[bin_of(v.x)], 1u);
                atomicAdd(&hist2048[bin_of(v.y)], 1u);
                atomicAdd(&hist2048[bin_of(v.z)], 1u);
                atomicAdd(&hist2048[bin_of(v.w)], 1u);
            }
            __syncthreads();
            if (tid < 64) {              // wave 0: chunked suffix scan
                int carry = 0;
                for (int c = 31; c >= 0; --c) {
                    int h = (int)hist2048[c * 64 + lane];
                    int ss = h;
#pragma unroll
                    for (int off = 1; off < 64; off <<= 1) {
                        int t = __shfl_down(ss, off, 64);
                        if (lane + off < 64) ss += t;
                    }
                    int S = ss + carry;
                    int Snext = S - h;
                    if (S >= PRE && Snext < PRE) {
                        u.p2.bsel   = c * 64 + lane;
                        u.p2.tprime = PRE - Snext;
                    }
                    carry += __shfl(ss, 0, 64);
                }
            }
            __syncthreads();
            const int bsel   = u.p2.bsel;
            const int tprime = u.p2.tprime;
            for (int n = tid; n < F4PB; n += 256) {
                float4 v = src[n];
                float sv[4] = {v.x, v.y, v.z, v.w};
#pragma unroll
                for (int c = 0; c < 4; ++c) {
                    int bn = bin_of(sv[c]);
                    if (bn >= bsel) {
                        u64 key = make_key(sv[c], 4 * n + c, bn);
                        if (bn > bsel) {
                            int q = atomicAdd(&u.p2.cnt, 1);
                            if (q < 2048) u.p2.dest[q] = key;
                        } else {
                            int t = atomicAdd(&u.p2.nc, 1);
                            if (t < CANDCAP) cand[t] = key;
                        }
                    }
                }
            }
            __syncthreads();
            const int nc = min(u.p2.nc, CANDCAP);
            for (int i = tid; i < nc; i += 256) {
                uint32_t vi = (uint32_t)(cand[i] >> 32);
                int g = 0, e = 0;
                for (int j = 0; j < nc; ++j) {
                    uint32_t vj = (uint32_t)(cand[j] >> 32);
                    g += (vj > vi);
                    e += (vj == vi);
                }
                if (g < tprime && g + e >= tprime) u.p2.pivot = vi;
            }
            __syncthreads();
            const uint32_t pivot = u.p2.pivot;
            for (int i = tid; i < nc; i += 256) {
                uint32_t vi = (uint32_t)(cand[i] >> 32);
                if (vi >= pivot) {
                    int q = atomicAdd(&u.p2.cnt, 1);
                    if (q < 2048) u.p2.dest[q] = cand[i];
                }
            }
            __syncthreads();
            const int tt = min(u.p2.cnt, 2048);
            for (int q = tt + tid; q < SORTN; q += 256) u.p2.dest[q] = 0ull;
            __syncthreads();
            for (int k = 2; k <= SORTN; k <<= 1) {
                for (int j = k >> 1; j > 0; j >>= 1) {
                    for (int p = tid; p < SORTN / 2; p += 256) {
                        int i = 2 * p - (p & (j - 1));
                        int l = i | j;
                        u64 a = u.p2.dest[i], c = u.p2.dest[l];
                        bool up = ((i & k) == 0);
                        bool sw = up ? (a < c) : (a > c);
                        if (sw) { u.p2.dest[i] = c; u.p2.dest[l] = a; }
                    }
                    __syncthreads();
                }
            }
            for (int r = tid; r < SORTN; r += 256)
                g_sorted[(size_t)b * SORTN + r] = u.p2.dest[r];
        }
    }
    __syncthreads();    // dest reads done; PBL may overlay

    // ==================== P3: decode + supmat + supT (LDS) =================
    {
        const float4* dl = deltas + (size_t)b * N;
#pragma unroll
        for (int k = 0; k < 2; ++k) {
            int r = tid + k * 256;
            u.pb.box[r] = decode_key(g_sorted[(size_t)b * SORTN + r], dl,
                                     anchors, N);
        }
        __syncthreads();

        for (int idx = tid; idx < TILE * 16; idx += 256) {
            int row = idx & (TILE - 1);      // lanes vary row
            int w   = idx >> 9;              // wave-uniform
            int jbase = w << 5;
            float4 bi = u.pb.box[row];
            float  ai = area_of(bi);
            uint32_t bits = 0u;
            if (jbase + 31 > row) {
#pragma unroll
                for (int c = 0; c < 32; ++c) {
                    int j = jbase + c;
                    float4 bj = u.pb.box[j];     // wave-broadcast
                    float  aj = area_of(bj);
                    bool gt = (j > row) & iou_gt(bi, ai, bj, aj);
                    bits |= ((uint32_t)gt) << c;
                }
            }
            u.pb.supmat[row][w] = bits;
        }

        for (int t = tid; t < TILE * 2; t += 256) {
            int C  = t >> 1;
            int w2 = t & 1;
            int q  = C >> 6;
            float4 bc = u.pb.box[C];
            float  ac = area_of(bc);
            uint32_t bits = 0u;
#pragma unroll
            for (int c = 0; c < 32; ++c) {
                int R = q * 64 + w2 * 32 + c;
                float4 br = u.pb.box[R];
                float  ar = area_of(br);
                bool gt = (R < C) & iou_gt(br, ar, bc, ac);
                bits |= ((uint32_t)gt) << c;
            }
            ((uint32_t*)&u.pb.supT64[C])[w2] = bits;
        }
    }
    __syncthreads();

    // ==================== P4: greedy sweep + output (wave 0) ===============
    if (tid < 64) {
        uint32_t removedw = 0u;          // lanes 0..15: removed word
        int kc = 0, nq = 0;
        for (int q = 0; q < TILE / 64; ++q) {
            u64 cw = u.pb.supT64[q * 64 + lane];
            const int cbase = q << 6;
            uint32_t rlo = (uint32_t)__builtin_amdgcn_readlane((int)removedw, 2 * q);
            uint32_t rhi = (uint32_t)__builtin_amdgcn_readlane((int)removedw, 2 * q + 1);
            u64 avail = ~(((u64)rhi << 32) | rlo);
            u64 K = 0ull;
            while (avail) {              // ballot-based greedy resolve
                int i = __ffsll((long long)avail) - 1;
                K |= (1ull << i);
                u64 supp = __ballot(((cw >> i) & 1ull) != 0ull);
                avail &= ~(supp | (1ull << i));
            }
            if (lane == 0) u.pb.keepbits[q] = K;
            kc += __popcll(K);
            nq = q + 1;
            if (kc >= POST) break;
            if (K) {                     // masked propagation from LDS
                const int w = lane & 15;
                const int g = lane >> 4;
                uint32_t acc = 0u;
#pragma unroll
                for (int r = 0; r < 16; ++r) {
                    uint32_t v = u.pb.supmat[cbase + g * 16 + r][w];
                    uint32_t m = (uint32_t)0 - (uint32_t)((K >> (g * 16 + r)) & 1ull);
                    acc |= (v & m);
                }
                acc |= (uint32_t)__shfl_xor((int)acc, 16, 64);
                acc |= (uint32_t)__shfl_xor((int)acc, 32, 64);
                if (lane < 16) removedw |= acc;
            }
        }
        {
            int base = 0;
            for (int q = 0; q < nq; ++q) {
                u64 kbq = u.pb.keepbits[q];
                int pos = base + __popcll(kbq & ((1ull << lane) - 1));
                if (((kbq >> lane) & 1ull) && pos < POST)
                    u.pb.kept[pos] = (uint32_t)(q * 64 + lane);
                base += __popcll(kbq);
            }
        }
        int kcf = min(kc, POST);         // wave-uniform
        const bool fellback = (kcf < POST);

        // fallback scratch aliases this batch's dead g_pairs region
        float4* fb = (float4*)(g_pairs + (size_t)b * SL * KBUF);

        if (fellback) {
            const float4* dl = deltas + (size_t)b * N;
            for (int r = lane; r < PRE; r += 64)
                fb[r] = decode_key(g_sorted[(size_t)b * SORTN + r], dl,
                                   anchors, N);
            for (int w = lane; w < (PRE - TILE + 31) / 32; w += 64)
                u.pb.fmask[w] = 0u;
            for (int j = TILE + lane; j < PRE; j += 64) {
                float4 bj = fb[j];
                float  aj = area_of(bj);
                bool supd = false;
                for (int k = 0; k < kcf; ++k) {
                    int i = (int)u.pb.kept[k];
                    float4 bi = fb[i];
                    if (iou_gt(bi, area_of(bi), bj, aj)) { supd = true; break; }
                }
                if (supd)
                    atomicOr(&u.pb.fmask[(j - TILE) >> 5], 1u << ((j - TILE) & 31));
            }
            int i = TILE;
            while (i < PRE && kcf < POST) {
                while (i < PRE &&
                       ((u.pb.fmask[(i - TILE) >> 5] >> ((i - TILE) & 31)) & 1u)) ++i;
                if (i >= PRE) break;
                if (lane == 0) u.pb.kept[kcf] = (uint32_t)i;
                ++kcf;
                if (kcf >= POST) break;
                float4 bi = fb[i];
                float  ai = area_of(bi);
                for (int j = i + 1 + lane; j < PRE; j += 64) {
                    float4 bj = fb[j];
                    if (iou_gt(bi, ai, bj, area_of(bj)))
                        atomicOr(&u.pb.fmask[(j - TILE) >> 5],
                                 1u << ((j - TILE) & 31));
                }
                ++i;
            }
        }

        float4* ob = out + (size_t)b * POST;
        for (int r = lane; r < POST; r += 64) {
            float4 o = make_float4(0.f, 0.f, 0.f, 0.f);
            if (r < kcf) {
                int ki = (int)u.pb.kept[r];
                float4 bx = fellback ? fb[ki] : u.pb.box[ki];
                o.x = fminf(fmaxf(bx.x, 0.f), 1.f);
                o.y = fminf(fmaxf(bx.y, 0.f), 1.f);
                o.z = fminf(fmaxf(bx.z, 0.f), 1.f);
                o.w = fminf(fmaxf(bx.w, 0.f), 1.f);
            }
            ob[r] = o;
        }
    }
}

extern "C" void kernel_launch(void* const* d_in, const int* in_sizes, int n_in,
                              void* d_out, int out_size, void* d_ws, size_t ws_size,
                              hipStream_t stream) {
    const float4* deltas  = (const float4*)d_in[0];
    const float*  labels  = (const float*)d_in[1];
    const float4* anchors = (const float4*)d_in[2];
    const float4* score4  = (const float4*)labels;
    float4*       outp    = (float4*)d_out;
    int N = in_sizes[2] / 4;            // 90000
    int B = in_sizes[1] / N;            // 64

    // workspace: pairs | sorted | shist | scnt | cnt
    char* ws = (char*)d_ws;
    const size_t SZ_PAIRS  = (size_t)B * SL * KBUF * 8;   // also fb scratch
    const size_t SZ_SORTED = (size_t)B * SORTN * 8;
    const size_t SZ_SHIST  = (size_t)B * SL * 64 * 4;
    const size_t SZ_SCNT   = (size_t)B * SL * 4;
    u64*      g_pairs  = (u64*)ws;
    u64*      g_sorted = (u64*)(ws + SZ_PAIRS);
    uint32_t* g_shist  = (uint32_t*)(ws + SZ_PAIRS + SZ_SORTED);
    int*      g_scnt   = (int*)(ws + SZ_PAIRS + SZ_SORTED + SZ_SHIST);
    int*      g_cnt    = (int*)(ws + SZ_PAIRS + SZ_SORTED + SZ_SHIST + SZ_SCNT);

    hipMemsetAsync((void*)g_cnt, 0, (size_t)B * 4, stream);   // 256 B
    dataflow_kernel<<<B * SL, 256, 0, stream>>>(
        score4, deltas, anchors, g_pairs, g_scnt, g_shist, g_sorted,
        g_cnt, outp, N);
}

// Round 18
// 75.656 us; speedup vs baseline: 4.5807x; 4.5807x over previous
//
#include <hip/hip_runtime.h>
#include <stdint.h>

// RPN RoI proposal, 4-kernel pipeline, no pre-zeroed state. R18 = exact
// revert to R14 (best measured: 75.7us, absmax 0). Structural experiments
// R15-R17 (cooperative mega-kernel 101us, per-batch dataflow chaining
// 346us) both regressed: phase-parallelism across blocks via the HW
// scheduler beats removing node boundaries.
//  K1 (B*16 x 256): threshold gather (bin>=CONS) -> bin-grouped per-slice
//     segments + per-slice 64-bin hist. key = flip(f32)<<32 | bin<<20 |
//     (0xFFFFF-idx): u64 desc == lax.top_k order (incl. tie-break).
//  K2 (B x 1024): scatter via scanned hist tables; zero-barrier per-wave
//     segment bitonic sorts -> g_sorted. Exact hist-2048 fallback in-branch
//     (total<2000 / >4096 / slice>KBUF / bin>128; never taken).
//  K4 (B*16 x 256): decode 512 ranks into LDS; 32 rows x 16 words/block ->
//     g_supmat; s<8 emit transposed diag col-words g_supT; s==0 writes
//     g_boxes[0..512).
//  K5 (B x 64): chunked greedy sweep (ffs+ballot resolve; masked pipelined
//     propagation); early-exit at 300; exact fallback (decodes 2000 boxes;
//     never taken); write clipped [300,4] zero-padded.

#define PRE 2000
#define POST 300
#define TILE 512
#define IOU_THR 0.7f
#define EPSV 1e-8f
#define SORTN 2048
#define NBINS 2048
#define DESTCAP 4096
#define CANDCAP 512
#define CONS 1984
#define SL 16
#define KBUF 768

typedef unsigned long long u64;

__device__ __forceinline__ uint32_t flip_f32(uint32_t b) {
    return b ^ ((uint32_t)((int32_t)b >> 31) | 0x80000000u);
}

__device__ __forceinline__ int bin_of(float s) {
    int bn = (int)(s * 2048.0f);
    return min(max(bn, 0), NBINS - 1);
}

__device__ __forceinline__ u64 make_key(float s, int idx, int bn) {
    uint32_t ub = flip_f32(__float_as_uint(s));
    return ((u64)ub << 32) | ((uint32_t)bn << 20) |
           (uint32_t)(0xFFFFF - idx);
}

__device__ __forceinline__ bool iou_gt(const float4& bi, float ai,
                                       const float4& bj, float aj) {
    float yy1 = fmaxf(bi.x, bj.x);
    float xx1 = fmaxf(bi.y, bj.y);
    float yy2 = fminf(bi.z, bj.z);
    float xx2 = fminf(bi.w, bj.w);
    float inter = fmaxf(yy2 - yy1, 0.f) * fmaxf(xx2 - xx1, 0.f);
    float iou = inter / (ai + aj - inter + EPSV);
    return iou > IOU_THR;
}

__device__ __forceinline__ float area_of(const float4& bx) {
    return fmaxf(bx.z - bx.x, 0.f) * fmaxf(bx.w - bx.y, 0.f);
}

// decode one key -> box (identical expression everywhere -> bit-exact)
__device__ __forceinline__ float4 decode_key(u64 key, const float4* dl,
                                             const float4* anchors, int N) {
    uint32_t idx = 0xFFFFFu - (uint32_t)(key & 0xFFFFFull);
    if (idx >= (uint32_t)N) return make_float4(0.f, 0.f, 0.f, 0.f);
    float4 d  = dl[idx];
    float4 an = anchors[idx];
    float ah  = an.z - an.x;
    float aw  = an.w - an.y;
    float acy = an.x + 0.5f * ah;
    float acx = an.y + 0.5f * aw;
    float h   = expf(d.z) * ah;
    float w   = expf(d.w) * aw;
    float cy  = d.x * ah + acy;
    float cx  = d.y * aw + acx;
    float y1  = cy - 0.5f * h;
    float x1  = cx - 0.5f * w;
    return make_float4(y1, x1, y1 + h, x1 + w);
}

__device__ __forceinline__ u64 cs_keep(u64 v, u64 pv, int i, int j, int k) {
    bool lower   = ((i & j) == 0);
    bool desc    = ((i & k) == 0);
    bool keepmax = (desc == lower);
    u64 mx = v > pv ? v : pv;
    u64 mn = v > pv ? pv : v;
    return keepmax ? mx : mn;
}

// ---------------- K1: threshold gather + per-slice binning -----------------
__global__ __launch_bounds__(256) void k1_gather(
    const float4* __restrict__ score4,
    u64* __restrict__ g_pairs,           // [B*SL*KBUF] bin-grouped per slice
    int* __restrict__ g_scnt,            // [B*SL] raw counts
    uint32_t* __restrict__ g_shist,      // [B*SL*64] per-slice bin hist
    int N)
{
    const int blk = blockIdx.x;
    const int b   = blk / SL;
    const int s   = blk % SL;
    const int tid = threadIdx.x;
    const int lane = tid & 63;
    const int F4PB = N >> 2;
    const int F4PS = (F4PB + SL - 1) / SL;

    __shared__ u64 keybuf[KBUF];
    __shared__ u64 binbuf[KBUF];
    __shared__ uint32_t hist64[64];
    __shared__ int base64[64];
    __shared__ uint32_t cur64[64];
    __shared__ int kcnt;

    if (tid < 64) { hist64[tid] = 0u; cur64[tid] = 0u; }
    if (tid == 0) kcnt = 0;
    __syncthreads();

    const float4* src = score4 + (size_t)b * F4PB;
    const int n0 = s * F4PS, n1 = min(n0 + F4PS, F4PB);
    for (int n = n0 + tid; n < n1; n += 256) {
        float4 v = src[n];
        float sv[4] = {v.x, v.y, v.z, v.w};
#pragma unroll
        for (int c = 0; c < 4; ++c) {
            int bn = bin_of(sv[c]);
            if (bn >= CONS) {
                int q = atomicAdd(&kcnt, 1);
                if (q < KBUF) keybuf[q] = make_key(sv[c], 4 * n + c, bn);
            }
        }
    }
    __syncthreads();

    const int raw = kcnt;
    const int lc  = min(raw, KBUF);

    for (int i = tid; i < lc; i += 256) {
        int b64 = (int)((keybuf[i] >> 20) & 0xFFFu) - CONS;  // in [0,64)
        atomicAdd(&hist64[b64], 1u);
    }
    __syncthreads();

    if (tid < 64) {
        int h = (int)hist64[lane];
        int ssum = h;
#pragma unroll
        for (int off = 1; off < 64; off <<= 1) {
            int t = __shfl_down(ssum, off, 64);
            if (lane + off < 64) ssum += t;
        }
        base64[lane] = ssum - h;         // #keys in bins > lane (desc order)
    }
    __syncthreads();

    for (int i = tid; i < lc; i += 256) {
        u64 key = keybuf[i];
        int b64 = (int)((key >> 20) & 0xFFFu) - CONS;
        int p = (int)atomicAdd(&cur64[b64], 1u);
        binbuf[base64[b64] + p] = key;   // within-bin order arbitrary; sorted later
    }
    __syncthreads();

    if (tid == 0) g_scnt[b * SL + s] = raw;
    if (tid < 64) g_shist[((size_t)b * SL + s) * 64 + tid] = hist64[tid];
    u64* gp = g_pairs + ((size_t)b * SL + s) * KBUF;
    for (int i = tid; i < lc; i += 256) gp[i] = binbuf[i];
}

// ---------------- K2: arithmetic scatter + segmented sort ------------------
__global__ __launch_bounds__(1024) void k2_sort(
    const float4* __restrict__ score4,
    const u64*  __restrict__ g_pairs,
    const int*  __restrict__ g_scnt,
    const uint32_t* __restrict__ g_shist,
    u64* __restrict__ g_sorted,
    int N)
{
    const int b    = blockIdx.x;
    const int tid  = threadIdx.x;
    const int lane = tid & 63;
    const int wv   = tid >> 6;

    __shared__ u64 dest[DESTCAP];
    __shared__ uint32_t hist2048[NBINS]; // fallback only
    __shared__ u64 cand[CANDCAP];        // fallback only
    __shared__ uint32_t shist[SL][64];
    __shared__ int srcb[SL][64];
    __shared__ int sbase[SL][64];
    __shared__ int tot64[64];
    __shared__ int segbase64[64];
    __shared__ uint32_t wtot[16];
    __shared__ int sh_flag, sh_total, sh_bsel, sh_tprime, sh_cnt, sh_nc;
    __shared__ uint32_t sh_pivot;

    const int F4PB = N >> 2;

    shist[tid >> 6][tid & 63] = g_shist[(size_t)b * SL * 64 + tid];
    if (tid == 0) {
        int f = 0;
#pragma unroll
        for (int s = 0; s < SL; ++s)
            if (g_scnt[b * SL + s] > KBUF) f = 1;
        sh_flag = f;
    }
    __syncthreads();

    if (tid < 64) {
        int acc = 0;
#pragma unroll
        for (int s = 0; s < SL; ++s) acc += (int)shist[s][tid];
        tot64[tid] = acc;
        if (acc > 128) sh_flag = 1;      // per-wave 2-reg sort cap
    }
    {
        int h = (int)shist[wv][lane];
        int ssum = h;
#pragma unroll
        for (int off = 1; off < 64; off <<= 1) {
            int t = __shfl_down(ssum, off, 64);
            if (lane + off < 64) ssum += t;
        }
        srcb[wv][lane] = ssum - h;       // within-slice base (desc bins)
    }
    __syncthreads();

    if (tid < 64) {
        int t0 = tot64[lane];
        int ssum = t0;
#pragma unroll
        for (int off = 1; off < 64; off <<= 1) {
            int t = __shfl_down(ssum, off, 64);
            if (lane + off < 64) ssum += t;
        }
        segbase64[lane] = ssum - t0;
        if (lane == 0) sh_total = ssum;
    }
    __syncthreads();
    const int total = sh_total;
    if (tid == 0 && (total < PRE || total > DESTCAP)) sh_flag = 1;
    {
        int s   = tid >> 6;
        int b64 = tid & 63;
        int pre = 0;
        for (int s2 = 0; s2 < s; ++s2) pre += (int)shist[s2][b64];
        sbase[s][b64] = segbase64[b64] + pre;
    }
    __syncthreads();
    const bool flag = (sh_flag != 0);

    if (!flag) {
        const int cs = min(g_scnt[b * SL + wv], KBUF);
        const u64* gp = g_pairs + ((size_t)b * SL + wv) * KBUF;
        for (int i = lane; i < cs; i += 64) {
            u64 key = gp[i];
            int b64 = (int)((key >> 20) & 0xFFFu) - CONS;
            dest[sbase[wv][b64] + (i - srcb[wv][b64])] = key;
        }
        __syncthreads();
        for (int sgi = wv; sgi < 64; sgi += 16) {
            int n = tot64[sgi];
            if (n <= 0) continue;
            int base = segbase64[sgi];
            if (n <= 64) {
                u64 e = (lane < n) ? dest[base + lane] : 0ull;
#pragma unroll
                for (int k = 2; k <= 64; k <<= 1)
                    for (int j = k >> 1; j > 0; j >>= 1)
                        e = cs_keep(e, __shfl_xor(e, j, 64), lane, j, k);
                if (lane < n) dest[base + lane] = e;
            } else {                     // 65..128
                u64 e0 = (lane < n) ? dest[base + lane] : 0ull;
                u64 e1 = (lane + 64 < n) ? dest[base + lane + 64] : 0ull;
#pragma unroll
                for (int k = 2; k <= 128; k <<= 1) {
                    for (int j = k >> 1; j > 0; j >>= 1) {
                        if (j == 64) {
                            u64 a = e0, c = e1;
                            e0 = cs_keep(a, c, lane, 64, k);
                            e1 = cs_keep(c, a, lane + 64, 64, k);
                        } else {
                            e0 = cs_keep(e0, __shfl_xor(e0, j, 64), lane, j, k);
                            e1 = cs_keep(e1, __shfl_xor(e1, j, 64), lane + 64, j, k);
                        }
                    }
                }
                if (lane < n) dest[base + lane] = e0;
                if (lane + 64 < n) dest[base + lane + 64] = e1;
            }
        }
        __syncthreads();
        g_sorted[(size_t)b * SORTN + tid]        = dest[tid];
        g_sorted[(size_t)b * SORTN + tid + 1024] = dest[tid + 1024];
    } else {
        // exact fallback: hist-based top-2000 (never taken on this data)
        hist2048[tid] = 0u; hist2048[tid + 1024] = 0u;
        if (tid == 0) { sh_cnt = 0; sh_nc = 0; }
        __syncthreads();
        const float4* src = score4 + (size_t)b * F4PB;
        for (int n = tid; n < F4PB; n += 1024) {
            float4 v = src[n];
            atomicAdd(&hist2048[bin_of(v.x)], 1u);
            atomicAdd(&hist2048[bin_of(v.y)], 1u);
            atomicAdd(&hist2048[bin_of(v.z)], 1u);
            atomicAdd(&hist2048[bin_of(v.w)], 1u);
        }
        __syncthreads();
        {
            const int i0 = wv * 128 + lane;
            const int i1 = i0 + 64;
            int h0 = (int)hist2048[i0];
            int h1 = (int)hist2048[i1];
            int s0 = h0, s1 = h1;
#pragma unroll
            for (int off = 1; off < 64; off <<= 1) {
                int t0 = __shfl_down(s0, off, 64);
                int t1 = __shfl_down(s1, off, 64);
                if (lane + off < 64) { s0 += t0; s1 += t1; }
            }
            int sum_h1 = __shfl(s1, 0, 64);
            if (lane == 0) wtot[wv] = (uint32_t)(__shfl(s0, 0, 64) + sum_h1);
            __syncthreads();
            int offtot = 0;
            for (int w2 = wv + 1; w2 < 16; ++w2) offtot += (int)wtot[w2];
            int S0 = s0 + sum_h1 + offtot;
            int S1 = s1 + offtot;
            if (S0 >= PRE && S0 - h0 < PRE) { sh_bsel = i0; sh_tprime = PRE - (S0 - h0); }
            if (S1 >= PRE && S1 - h1 < PRE) { sh_bsel = i1; sh_tprime = PRE - (S1 - h1); }
        }
        __syncthreads();
        const int bsel   = sh_bsel;
        const int tprime = sh_tprime;
        for (int n = tid; n < F4PB; n += 1024) {
            float4 v = src[n];
            float sv[4] = {v.x, v.y, v.z, v.w};
#pragma unroll
            for (int c = 0; c < 4; ++c) {
                int bn = bin_of(sv[c]);
                if (bn >= bsel) {
                    u64 key = make_key(sv[c], 4 * n + c, bn);
                    if (bn > bsel) {
                        int q = atomicAdd(&sh_cnt, 1);
                        if (q < SORTN) dest[q] = key;
                    } else {
                        int t = atomicAdd(&sh_nc, 1);
                        if (t < CANDCAP) cand[t] = key;
                    }
                }
            }
        }
        __syncthreads();
        const int nc = min(sh_nc, CANDCAP);
        for (int i = tid; i < nc; i += 1024) {
            uint32_t vi = (uint32_t)(cand[i] >> 32);
            int g = 0, e = 0;
            for (int j = 0; j < nc; ++j) {
                uint32_t vj = (uint32_t)(cand[j] >> 32);
                g += (vj > vi);
                e += (vj == vi);
            }
            if (g < tprime && g + e >= tprime) sh_pivot = vi;
        }
        __syncthreads();
        const uint32_t pivot = sh_pivot;
        for (int i = tid; i < nc; i += 1024) {
            uint32_t vi = (uint32_t)(cand[i] >> 32);
            if (vi >= pivot) {
                int q = atomicAdd(&sh_cnt, 1);
                if (q < SORTN) dest[q] = cand[i];
            }
        }
        __syncthreads();
        const int tt = min(sh_cnt, SORTN);
        for (int q = tt + tid; q < SORTN; q += 1024) dest[q] = 0ull;
        __syncthreads();
        {
            const int i0 = wv * 128 + lane;
            const int i1 = i0 + 64;
            u64 e0 = dest[i0];
            u64 e1 = dest[i1];
            for (int k = 2; k <= SORTN; k <<= 1) {
                for (int j = k >> 1; j > 0; j >>= 1) {
                    if (j >= 128) {
                        dest[i0] = e0;
                        dest[i1] = e1;
                        __syncthreads();
                        u64 p0 = dest[i0 ^ j];
                        u64 p1 = dest[i1 ^ j];
                        __syncthreads();
                        e0 = cs_keep(e0, p0, i0, j, k);
                        e1 = cs_keep(e1, p1, i1, j, k);
                    } else if (j == 64) {
                        u64 a = e0, c = e1;
                        e0 = cs_keep(a, c, i0, 64, k);
                        e1 = cs_keep(c, a, i1, 64, k);
                    } else {
                        e0 = cs_keep(e0, __shfl_xor(e0, j, 64), i0, j, k);
                        e1 = cs_keep(e1, __shfl_xor(e1, j, 64), i1, j, k);
                    }
                }
            }
            g_sorted[(size_t)b * SORTN + i0] = e0;
            g_sorted[(size_t)b * SORTN + i1] = e1;
        }
    }
}

// ---------------- K4: fused decode + suppression matrix + supT -------------
__global__ __launch_bounds__(256) void k4_supmat(
    const float4* __restrict__ deltas,
    const float4* __restrict__ anchors,
    const u64*  __restrict__ g_sorted,
    float4* __restrict__ g_boxes,        // [B*512]
    uint32_t* __restrict__ g_supmat,     // [B*512*16] row-major
    uint32_t* __restrict__ g_supT,       // [B*512*2]  diag col-words
    int N)
{
    const int b   = blockIdx.x >> 4;
    const int s   = blockIdx.x & 15;
    const int tid = threadIdx.x;

    __shared__ float4 box[TILE];

    const float4* dl = deltas + (size_t)b * N;
#pragma unroll
    for (int k = 0; k < 2; ++k) {
        int r = tid + k * 256;
        box[r] = decode_key(g_sorted[(size_t)b * SORTN + r], dl, anchors, N);
    }
    __syncthreads();

    if (s == 0) {
#pragma unroll
        for (int k = 0; k < 2; ++k) {
            int r = tid + k * 256;
            g_boxes[(size_t)b * TILE + r] = box[r];
        }
    }

    const int rbase = s * 32;
#pragma unroll
    for (int k = 0; k < 2; ++k) {
        int idx = tid + k * 256;
        int row = rbase + (idx & 31);
        int w   = idx >> 5;
        int jbase = w << 5;
        float4 bi = box[row];
        float  ai = area_of(bi);
        uint32_t bits = 0u;
        if (jbase + 31 > row) {
#pragma unroll
            for (int c = 0; c < 32; ++c) {
                int j = jbase + c;
                float4 bj = box[j];
                float  aj = area_of(bj);
                bool gt = (j > row) & iou_gt(bi, ai, bj, aj);  // branchless
                bits |= ((uint32_t)gt) << c;
            }
        }
        g_supmat[((size_t)b * TILE + row) * 16 + w] = bits;
    }

    if (s < 8 && tid < 128) {
        int q  = s;
        int j  = tid >> 1;
        int w2 = tid & 1;
        int C  = q * 64 + j;
        float4 bc = box[C];
        float  ac = area_of(bc);
        uint32_t bits = 0u;
#pragma unroll
        for (int c = 0; c < 32; ++c) {
            int R = q * 64 + w2 * 32 + c;
            float4 br = box[R];
            float  ar = area_of(br);
            bool gt = (R < C) & iou_gt(br, ar, bc, ac);
            bits |= ((uint32_t)gt) << c;
        }
        g_supT[((size_t)b * TILE + C) * 2 + w2] = bits;
    }
}

// ---------------- K5: ballot-resolve chunked greedy sweep ------------------
__global__ __launch_bounds__(64) void k5_sweep(
    const uint32_t* __restrict__ g_supmat,
    const u64*    __restrict__ g_supT64,   // [B*512] diag col-words
    const u64*    __restrict__ g_sorted,   // fallback decode source
    const float4* __restrict__ deltas,
    const float4* __restrict__ anchors,
    const float4* __restrict__ g_boxes,    // [B*512]
    float4* __restrict__ out,
    int N)
{
    const int b    = blockIdx.x;
    const int lane = threadIdx.x;

    __shared__ uint32_t kept[POST];
    __shared__ u64 sh_keepbits[TILE / 64];
    __shared__ int sh_kc;
    // fallback-only LDS (untouched on the common path)
    __shared__ float4 fbox[PRE];
    __shared__ float  farea[PRE];
    __shared__ uint32_t fmask[(PRE - TILE + 31) / 32];

    const u64* tdbase = g_supT64 + (size_t)b * TILE;

    uint32_t removedw = 0u;              // lanes 0..15: removed word
    int kc = 0, nq = 0;
    u64 cw_cur = tdbase[lane];
    for (int q = 0; q < TILE / 64; ++q) {
        u64 cw_next = (q < TILE / 64 - 1) ? tdbase[(q + 1) * 64 + lane] : 0ull;
        const int cbase = q << 6;
        uint32_t rlo = (uint32_t)__builtin_amdgcn_readlane((int)removedw, 2 * q);
        uint32_t rhi = (uint32_t)__builtin_amdgcn_readlane((int)removedw, 2 * q + 1);
        u64 avail = ~(((u64)rhi << 32) | rlo);
        u64 K = 0ull;
        while (avail) {                  // ballot-based greedy resolve
            int i = __ffsll((long long)avail) - 1;
            K |= (1ull << i);
            u64 supp = __ballot(((cw_cur >> i) & 1ull) != 0ull);
            avail &= ~(supp | (1ull << i));
        }
        if (lane == 0) sh_keepbits[q] = K;
        kc += __popcll(K);
        nq = q + 1;
        if (kc >= POST) break;
        if (K) {                         // masked pipelined propagation
            const int w = lane & 15;
            const int g = lane >> 4;
            const uint32_t* gs =
                g_supmat + ((size_t)b * TILE + cbase + g * 16) * 16 + w;
            uint32_t acc = 0u;
#pragma unroll
            for (int r = 0; r < 16; ++r) {
                uint32_t v = gs[(size_t)r * 16];
                uint32_t m = (uint32_t)0 - (uint32_t)((K >> (g * 16 + r)) & 1ull);
                acc |= (v & m);
            }
            acc |= (uint32_t)__shfl_xor((int)acc, 16, 64);
            acc |= (uint32_t)__shfl_xor((int)acc, 32, 64);
            if (lane < 16) removedw |= acc;
        }
        cw_cur = cw_next;
    }
    {
        int base = 0;
        for (int q = 0; q < nq; ++q) {
            u64 kbq = sh_keepbits[q];
            int pos = base + __popcll(kbq & ((1ull << lane) - 1));
            if (((kbq >> lane) & 1ull) && pos < POST)
                kept[pos] = (uint32_t)(q * 64 + lane);
            base += __popcll(kbq);
        }
        if (lane == 0) sh_kc = min(kc, POST);
    }
    __syncthreads();
    int kcf = sh_kc;
    const bool fellback = (kcf < POST);

    if (fellback) {
        // exact continuation (never taken on this data): decode everything
        const float4* dl = deltas + (size_t)b * N;
        for (int r = lane; r < PRE; r += 64) {
            float4 bx = decode_key(g_sorted[(size_t)b * SORTN + r], dl,
                                   anchors, N);
            fbox[r]  = bx;
            farea[r] = area_of(bx);
        }
        for (int w = lane; w < (PRE - TILE + 31) / 32; w += 64) fmask[w] = 0u;
        __syncthreads();
        for (int j = TILE + lane; j < PRE; j += 64) {
            float4 bj = fbox[j];
            float  aj = farea[j];
            bool supd = false;
            for (int k = 0; k < kcf; ++k) {
                int i = (int)kept[k];
                if (iou_gt(fbox[i], farea[i], bj, aj)) { supd = true; break; }
            }
            if (supd) atomicOr(&fmask[(j - TILE) >> 5], 1u << ((j - TILE) & 31));
        }
        __syncthreads();
        int i = TILE;
        while (i < PRE && kcf < POST) {
            while (i < PRE && ((fmask[(i - TILE) >> 5] >> ((i - TILE) & 31)) & 1u)) ++i;
            if (i >= PRE) break;
            if (lane == 0) kept[kcf] = (uint32_t)i;
            ++kcf;
            if (kcf >= POST) break;
            float4 bi = fbox[i];
            float  ai = farea[i];
            for (int j = i + 1 + lane; j < PRE; j += 64) {
                if (iou_gt(bi, ai, fbox[j], farea[j]))
                    atomicOr(&fmask[(j - TILE) >> 5], 1u << ((j - TILE) & 31));
            }
            ++i;
            __syncthreads();
        }
    }
    __syncthreads();

    float4* ob = out + (size_t)b * POST;
    for (int r = lane; r < POST; r += 64) {
        float4 o = make_float4(0.f, 0.f, 0.f, 0.f);
        if (r < kcf) {
            int ki = (int)kept[r];
            float4 bx = fellback ? fbox[ki]
                                 : g_boxes[(size_t)b * TILE + ki];
            o.x = fminf(fmaxf(bx.x, 0.f), 1.f);
            o.y = fminf(fmaxf(bx.y, 0.f), 1.f);
            o.z = fminf(fmaxf(bx.z, 0.f), 1.f);
            o.w = fminf(fmaxf(bx.w, 0.f), 1.f);
        }
        ob[r] = o;
    }
}

extern "C" void kernel_launch(void* const* d_in, const int* in_sizes, int n_in,
                              void* d_out, int out_size, void* d_ws, size_t ws_size,
                              hipStream_t stream) {
    const float4* deltas  = (const float4*)d_in[0];
    const float*  labels  = (const float*)d_in[1];
    const float4* anchors = (const float4*)d_in[2];
    const float4* score4  = (const float4*)labels;
    float4*       outp    = (float4*)d_out;
    const int N = in_sizes[2] / 4;      // 90000
    const int B = in_sizes[1] / N;      // 64

    // workspace (16B-aligned chunks), no zero-init required anywhere:
    // boxes | pairs | sorted | supmat | supT | shist | scnt
    char* ws = (char*)d_ws;
    const size_t SZ_BOXES  = (size_t)B * TILE * 16;
    const size_t SZ_PAIRS  = (size_t)B * SL * KBUF * 8;
    const size_t SZ_SORTED = (size_t)B * SORTN * 8;
    const size_t SZ_SUPMAT = (size_t)B * TILE * 16 * 4;
    const size_t SZ_SUPT   = (size_t)B * TILE * 8;
    const size_t SZ_SHIST  = (size_t)B * SL * 64 * 4;
    float4*   g_boxes  = (float4*)ws;
    u64*      g_pairs  = (u64*)(ws + SZ_BOXES);
    u64*      g_sorted = (u64*)(ws + SZ_BOXES + SZ_PAIRS);
    uint32_t* g_supmat = (uint32_t*)(ws + SZ_BOXES + SZ_PAIRS + SZ_SORTED);
    uint32_t* g_supT   = (uint32_t*)(ws + SZ_BOXES + SZ_PAIRS + SZ_SORTED + SZ_SUPMAT);
    uint32_t* g_shist  = (uint32_t*)(ws + SZ_BOXES + SZ_PAIRS + SZ_SORTED + SZ_SUPMAT + SZ_SUPT);
    int*      g_scnt   = (int*)((char*)g_shist + SZ_SHIST);

    k1_gather<<<B * SL, 256, 0, stream>>>(score4, g_pairs, g_scnt, g_shist, N);
    k2_sort<<<B, 1024, 0, stream>>>(score4, g_pairs, g_scnt, g_shist,
                                    g_sorted, N);
    k4_supmat<<<B * 16, 256, 0, stream>>>(deltas, anchors, g_sorted,
                                          g_boxes, g_supmat, g_supT, N);
    k5_sweep<<<B, 64, 0, stream>>>(g_supmat, (const u64*)g_supT, g_sorted,
                                   deltas, anchors, g_boxes, outp, N);
}